// Round 1
// baseline (339.669 us; speedup 1.0000x reference)
//
#include <hip/hip_runtime.h>
#include <hip/hip_bf16.h>

// SparseLinear: out[8192,128] = sum over COO entries (r,c,v): out[r,:] += v * x[c,:]
// Strategy: build CSR on device (hist -> scan -> scatter), then 1 wave per row,
// register accumulation, no fp32 atomics.

#define M_ROWS 8192
#define B_COLS 128

__global__ void zero_i32_kernel(int* __restrict__ p, int n) {
    int i = blockIdx.x * blockDim.x + threadIdx.x;
    if (i < n) p[i] = 0;
}

__global__ void hist_kernel(const int* __restrict__ rows, int nnz, int* __restrict__ counts) {
    int i = blockIdx.x * blockDim.x + threadIdx.x;
    if (i < nnz) atomicAdd(&counts[rows[i]], 1);
}

// Single block, 256 threads, scans 8192 counts -> exclusive prefix (in place),
// writes start[M]=nnz and initializes cursor[i]=start[i].
__global__ void scan_kernel(int* __restrict__ start, int* __restrict__ cursor) {
    __shared__ int sums[256];
    __shared__ int offs[257];
    int t = threadIdx.x;
    int base = t * 32;
    int local[32];
    int s = 0;
#pragma unroll
    for (int j = 0; j < 32; ++j) { local[j] = start[base + j]; s += local[j]; }
    sums[t] = s;
    __syncthreads();
    if (t == 0) {
        int acc = 0;
        for (int i = 0; i < 256; ++i) { offs[i] = acc; acc += sums[i]; }
        offs[256] = acc;
    }
    __syncthreads();
    int acc = offs[t];
#pragma unroll
    for (int j = 0; j < 32; ++j) {
        int c = local[j];
        start[base + j] = acc;
        cursor[base + j] = acc;
        acc += c;
    }
    if (t == 0) start[M_ROWS] = offs[256];
}

__global__ void scatter_kernel(const int* __restrict__ rows, const int* __restrict__ cols,
                               const float* __restrict__ vals, int nnz,
                               int* __restrict__ cursor, int2* __restrict__ pairs) {
    int i = blockIdx.x * blockDim.x + threadIdx.x;
    if (i < nnz) {
        int r = rows[i];
        int pos = atomicAdd(&cursor[r], 1);
        pairs[pos] = make_int2(cols[i], __float_as_int(vals[i]));
    }
}

// One wave (64 lanes) per output row; lane l owns columns 2l, 2l+1 (float2).
// Block of 256 threads = 4 rows.
__global__ void __launch_bounds__(256) spmm_csr_kernel(const int2* __restrict__ pairs,
                                                       const int* __restrict__ start,
                                                       const float* __restrict__ x,
                                                       float* __restrict__ out) {
    int wave = threadIdx.x >> 6;
    int lane = threadIdx.x & 63;
    int row = blockIdx.x * 4 + wave;
    int s = start[row];
    int e = start[row + 1];
    int c2 = lane * 2;
    float2 acc = make_float2(0.f, 0.f);
#pragma unroll 4
    for (int i = s; i < e; ++i) {
        int2 p = pairs[i];                 // broadcast across wave (same addr)
        float v = __int_as_float(p.y);
        const float2 xv = *(const float2*)(x + (size_t)p.x * B_COLS + c2);
        acc.x = fmaf(v, xv.x, acc.x);
        acc.y = fmaf(v, xv.y, acc.y);
    }
    *(float2*)(out + (size_t)row * B_COLS + c2) = acc;
}

// Fallback if workspace is too small: direct atomic scatter-add.
__global__ void atomic_spmm_kernel(const int* __restrict__ rows, const int* __restrict__ cols,
                                   const float* __restrict__ vals, int nnz,
                                   const float* __restrict__ x, float* __restrict__ out) {
    long long tid = (long long)blockIdx.x * blockDim.x + threadIdx.x;
    int e = (int)(tid >> 5);   // 32 groups of 4 columns
    int g = (int)(tid & 31);
    if (e < nnz) {
        int r = rows[e], c = cols[e];
        float v = vals[e];
        const float4 xv = *(const float4*)(x + (size_t)c * B_COLS + g * 4);
        float* o = out + (size_t)r * B_COLS + g * 4;
        atomicAdd(o + 0, v * xv.x);
        atomicAdd(o + 1, v * xv.y);
        atomicAdd(o + 2, v * xv.z);
        atomicAdd(o + 3, v * xv.w);
    }
}

extern "C" void kernel_launch(void* const* d_in, const int* in_sizes, int n_in,
                              void* d_out, int out_size, void* d_ws, size_t ws_size,
                              hipStream_t stream) {
    const int*   ids  = (const int*)d_in[0];
    const int    nnz  = in_sizes[0] / 2;
    const int*   rows = ids;
    const int*   cols = ids + nnz;
    const float* vals = (const float*)d_in[1];
    const float* x    = (const float*)d_in[2];
    float*       out  = (float*)d_out;

    // ws layout: start[M+1] ints | cursor[M+1] ints (pad keeps pairs 8B-aligned) | pairs[nnz] int2
    size_t need = (size_t)(M_ROWS + 1) * 4 * 2 + (size_t)nnz * 8;
    if (ws_size >= need) {
        int*  start  = (int*)d_ws;
        int*  cursor = start + (M_ROWS + 1);
        int2* pairs  = (int2*)(cursor + (M_ROWS + 1));

        zero_i32_kernel<<<(M_ROWS + 1 + 255) / 256, 256, 0, stream>>>(start, M_ROWS + 1);
        hist_kernel<<<(nnz + 255) / 256, 256, 0, stream>>>(rows, nnz, start);
        scan_kernel<<<1, 256, 0, stream>>>(start, cursor);
        scatter_kernel<<<(nnz + 255) / 256, 256, 0, stream>>>(rows, cols, vals, nnz, cursor, pairs);
        spmm_csr_kernel<<<M_ROWS / 4, 256, 0, stream>>>(pairs, start, x, out);
    } else {
        hipMemsetAsync(d_out, 0, (size_t)out_size * sizeof(float), stream);
        long long total = (long long)nnz * 32;
        atomic_spmm_kernel<<<(unsigned)((total + 255) / 256), 256, 0, stream>>>(rows, cols, vals, nnz, x, out);
    }
}